// Round 6
// baseline (545.855 us; speedup 1.0000x reference)
//
#include <hip/hip_runtime.h>
#include <hip/hip_bf16.h>

typedef __attribute__((ext_vector_type(8))) short short8;
typedef __attribute__((ext_vector_type(4))) float f32x4;

#define INF_F 3.4e38f

__device__ __forceinline__ void gload16(const void* g, void* l) {
    __builtin_amdgcn_global_load_lds((const __attribute__((address_space(1))) unsigned*)g,
                                     (__attribute__((address_space(3))) unsigned*)l, 16, 0, 0);
}

#define SBAR() do { __builtin_amdgcn_s_barrier(); __builtin_amdgcn_sched_barrier(0); } while(0)
#define VMCNT4() asm volatile("s_waitcnt vmcnt(4)" ::: "memory")
#define VMCNT0() asm volatile("s_waitcnt vmcnt(0)" ::: "memory")
#define MF(a,b,cc) __builtin_amdgcn_mfma_f32_16x16x32_bf16((a),(b),(cc),0,0,0)

// ---------------- fp32 -> bf16 + row norms (512 cols) for BOTH fv and mb, + init ----------------
__global__ void k_conv(const float* __restrict__ fv, const float* __restrict__ mbp,
                       unsigned short* __restrict__ fvb, unsigned short* __restrict__ mbb,
                       float* __restrict__ fnorm, float* __restrict__ mnorm,
                       float* ps_sq, int* ncand, float* cand_val) {
    int t = threadIdx.x, wid = t >> 6, lane = t & 63;
    if (blockIdx.x == 0) {
        if (t == 0) ncand[0] = 0;
        if (t < 64) ((unsigned*)cand_val)[t] = 0x7f800000u;
    }
    int row = blockIdx.x * 4 + wid;
    const float* in; unsigned short* outb; float* norm; int r;
    if (row < 8192) {
        in = fv; outb = fvb; norm = fnorm; r = row;
        if (lane == 0) ((unsigned*)ps_sq)[row] = 0x7f800000u;   // +inf init
    } else if (row < 33192) {
        in = mbp; outb = mbb; norm = mnorm; r = row - 8192;
    } else return;
    const float4* p = (const float4*)(in + (size_t)r * 512) + lane * 2;
    float4 a = p[0], b = p[1];
    float n = a.x*a.x + a.y*a.y + a.z*a.z + a.w*a.w
            + b.x*b.x + b.y*b.y + b.z*b.z + b.w*b.w;
    float vals[8] = {a.x, a.y, a.z, a.w, b.x, b.y, b.z, b.w};
    unsigned short h[8];
    #pragma unroll
    for (int e = 0; e < 8; ++e) {
        unsigned u = __float_as_uint(vals[e]);
        h[e] = (unsigned short)((u + 0x7fffu + ((u >> 16) & 1u)) >> 16);  // RNE
    }
    *(uint4*)(outb + (size_t)r * 512 + lane * 8) = *(uint4*)h;
    #pragma unroll
    for (int s = 1; s < 64; s <<= 1) n += __shfl_xor(n, s, 64);
    if (lane == 0) norm[r] = n;
}

// ---------------- 256x256 8-phase GEMM + per-row min (T2+T3+T4+T5) ----------------
// LDS per slot: A[2kh][16KB plane] + B[2kh][16KB plane]; plane = 128 rows x 64 elems
// (rows R and R+128 share a 128B LDS row: pr=R&127, half=R>>7), group-swizzled:
// elem (R, kh*32+c*8) at plane_byte pr*128 + ((half*4+c)^(pr&7))*16.  2 slots = 128 KiB.
// Group t (tile t, slot t&1) phases: ph1 kh0 mi0-3 (+B kh0) | stage t+1 A-kh1
//   ph2 kh0 mi4-7 | stage t+1 B-kh1 ; ph3 kh1 mi0-3 (+B kh1) | stage t+2 A-kh0
//   ph4 kh1 mi4-7 | stage t+2 B-kh0 ; vmcnt(4) (t<6) / vmcnt(0) (t==6) + barrier.
// Liveness: every stage target's readers completed >=1 barrier earlier; vmcnt(4)
// at group end completes all 4 half-tiles of tile t+1 (queue depth 12 -> 4).
__global__ __launch_bounds__(512, 2)
void k_gemm_min(const unsigned short* __restrict__ A, const unsigned short* __restrict__ B,
                const float* __restrict__ fnorm, const float* __restrict__ mnorm,
                float* __restrict__ ps_sq) {
    __shared__ unsigned short sh[65536];
    int tid = threadIdx.x, wid = tid >> 6, lane = tid & 63;
    int l15 = lane & 15, c = lane >> 4;
    int bid = blockIdx.x, pos = bid >> 3;
    int rb = ((bid & 7) << 2) | (pos & 3);   // 0..31 (XCD-chunked: 4 row-blocks/XCD)
    int cb = pos >> 2;                        // 0..97
    int brow = rb * 256, bcol = cb * 256;
    int wr = wid >> 2, wc = wid & 3;          // 2M x 4N wave grid

    // stage source decode (l = 0,1 sweeps of 512 threads x 16B per half-tile plane)
    int grow0, grow1, c80, c81;
    { int i = tid;       int pr = i >> 3, gp = i & 7, g = gp ^ (pr & 7); grow0 = ((g >> 2) << 7) + pr; c80 = (g & 3) * 8; }
    { int i = 512 + tid; int pr = i >> 3, gp = i & 7, g = gp ^ (pr & 7); grow1 = ((g >> 2) << 7) + pr; c81 = (g & 3) * 8; }
    const unsigned short* gA0 = A + (size_t)(brow + grow0) * 512 + c80;
    const unsigned short* gA1 = A + (size_t)(brow + grow1) * 512 + c81;
    int sb0 = bcol + grow0; if (sb0 > 24999) sb0 = 24999;
    int sb1 = bcol + grow1; if (sb1 > 24999) sb1 = 24999;
    const unsigned short* gB0 = B + (size_t)sb0 * 512 + c80;
    const unsigned short* gB1 = B + (size_t)sb1 * 512 + c81;

#define STAGE_A(TT, KH, SLOT) do { \
        gload16(gA0 + (TT)*64 + (KH)*32, sh + (SLOT)*32768 + (KH)*8192 + wid*512); \
        gload16(gA1 + (TT)*64 + (KH)*32, sh + (SLOT)*32768 + (KH)*8192 + 4096 + wid*512); } while(0)
#define STAGE_B(TT, KH, SLOT) do { \
        gload16(gB0 + (TT)*64 + (KH)*32, sh + (SLOT)*32768 + 16384 + (KH)*8192 + wid*512); \
        gload16(gB1 + (TT)*64 + (KH)*32, sh + (SLOT)*32768 + 16384 + (KH)*8192 + 4096 + wid*512); } while(0)
#define FRAG(MOFF, KK, RV) (*(const short8*)&sh[cur*32768 + (MOFF) + (KK)*8192 + ((RV)&127)*64 + (((((RV)>>7)<<2)+c)^((RV)&7))*8])

#define PHASE(QB, KK, LOADB, STAGES, TAIL) do { \
        af0 = FRAG(0, KK, wr*128 + (QB+0)*16 + l15); \
        af1 = FRAG(0, KK, wr*128 + (QB+1)*16 + l15); \
        af2 = FRAG(0, KK, wr*128 + (QB+2)*16 + l15); \
        af3 = FRAG(0, KK, wr*128 + (QB+3)*16 + l15); \
        if (LOADB) { \
            bf0 = FRAG(16384, KK, wc*64 +  0 + l15); \
            bf1 = FRAG(16384, KK, wc*64 + 16 + l15); \
            bf2 = FRAG(16384, KK, wc*64 + 32 + l15); \
            bf3 = FRAG(16384, KK, wc*64 + 48 + l15); \
        } \
        STAGES; \
        SBAR(); \
        __builtin_amdgcn_s_setprio(1); \
        acc[QB+0][0]=MF(af0,bf0,acc[QB+0][0]); acc[QB+0][1]=MF(af0,bf1,acc[QB+0][1]); \
        acc[QB+0][2]=MF(af0,bf2,acc[QB+0][2]); acc[QB+0][3]=MF(af0,bf3,acc[QB+0][3]); \
        acc[QB+1][0]=MF(af1,bf0,acc[QB+1][0]); acc[QB+1][1]=MF(af1,bf1,acc[QB+1][1]); \
        acc[QB+1][2]=MF(af1,bf2,acc[QB+1][2]); acc[QB+1][3]=MF(af1,bf3,acc[QB+1][3]); \
        acc[QB+2][0]=MF(af2,bf0,acc[QB+2][0]); acc[QB+2][1]=MF(af2,bf1,acc[QB+2][1]); \
        acc[QB+2][2]=MF(af2,bf2,acc[QB+2][2]); acc[QB+2][3]=MF(af2,bf3,acc[QB+2][3]); \
        acc[QB+3][0]=MF(af3,bf0,acc[QB+3][0]); acc[QB+3][1]=MF(af3,bf1,acc[QB+3][1]); \
        acc[QB+3][2]=MF(af3,bf2,acc[QB+3][2]); acc[QB+3][3]=MF(af3,bf3,acc[QB+3][3]); \
        __builtin_amdgcn_s_setprio(0); \
        TAIL; \
        SBAR(); \
    } while(0)

    f32x4 acc[8][4] = {};

    // prologue: tile0 all 4 half-tiles + tile1 kh0 halves; wait tile0 (4 loads stay in flight)
    STAGE_A(0, 0, 0); STAGE_B(0, 0, 0); STAGE_A(0, 1, 0); STAGE_B(0, 1, 0);
    STAGE_A(1, 0, 1); STAGE_B(1, 0, 1);
    VMCNT4();
    SBAR();

    #pragma unroll
    for (int t = 0; t < 8; ++t) {
        const int cur = t & 1, nxt = cur ^ 1;
        short8 af0, af1, af2, af3, bf0, bf1, bf2, bf3;
        PHASE(0, 0, 1, { if (t < 7) STAGE_A(t + 1, 1, nxt); }, {});
        PHASE(4, 0, 0, { if (t < 7) STAGE_B(t + 1, 1, nxt); }, {});
        PHASE(0, 1, 1, { if (t < 6) STAGE_A(t + 2, 0, cur); }, {});
        PHASE(4, 1, 0, { if (t < 6) STAGE_B(t + 2, 0, cur); },
              { if (t < 6) { VMCNT4(); } else if (t == 6) { VMCNT0(); } });
    }
#undef PHASE
#undef FRAG
#undef STAGE_A
#undef STAGE_B

    // epilogue: per-row min over this block's 256 cols, then global atomicMin
    float mnv[4];
    #pragma unroll
    for (int n = 0; n < 4; ++n) {
        int col = bcol + wc * 64 + n * 16 + l15;
        mnv[n] = (col < 25000) ? mnorm[col] : INF_F;
    }
    #pragma unroll
    for (int mi = 0; mi < 8; ++mi) {
        #pragma unroll
        for (int r = 0; r < 4; ++r) {
            float v = INF_F;
            #pragma unroll
            for (int n = 0; n < 4; ++n) v = fminf(v, mnv[n] - 2.0f * acc[mi][n][r]);
            #pragma unroll
            for (int s = 1; s < 16; s <<= 1) v = fminf(v, __shfl_xor(v, s, 64));
            if (l15 == 0) {
                int row = brow + wr * 128 + mi * 16 + c * 4 + r;
                float sq = v + fnorm[row];
                atomicMin((unsigned*)&ps_sq[row], __float_as_uint(sq));
            }
        }
    }
}

// ---------------- out0 + per-batch candidate gather ----------------
__global__ void k_cand(const float* __restrict__ ps_sq, float* __restrict__ out0,
                       int* ncand, int* cand_pix, int* cand_batch) {
    __shared__ float smax[4];
    __shared__ int scnt;
    int b = blockIdx.x, t = threadIdx.x, wid = t >> 6, lane = t & 63;
    const float* base = ps_sq + b * 1024;
    float v[4]; float m = -INF_F;
    #pragma unroll
    for (int i = 0; i < 4; ++i) {
        v[i] = base[t + i * 256];
        out0[b * 1024 + t + i * 256] = sqrtf(fmaxf(v[i], 0.0f));
        m = fmaxf(m, v[i]);
    }
    #pragma unroll
    for (int s = 1; s < 64; s <<= 1) m = fmaxf(m, __shfl_xor(m, s, 64));
    if (lane == 0) smax[wid] = m;
    if (t == 0) scnt = 0;
    __syncthreads();
    float bm = fmaxf(fmaxf(smax[0], smax[1]), fmaxf(smax[2], smax[3]));
    #pragma unroll
    for (int i = 0; i < 4; ++i) {
        if (v[i] >= bm - 8.0f) {            // margin >> 2x worst-case bf16 dot error
            int s = atomicAdd(&scnt, 1);
            if (s < 8) {
                int g = atomicAdd(ncand, 1);
                if (g < 64) { cand_pix[g] = b * 1024 + t + i * 256; cand_batch[g] = b; }
            }
        }
    }
}

// ---------------- exact fp32 min-dist, 4 candidates/block in NAMED registers ----------------
__global__ __launch_bounds__(256, 4)
void k_score(const float* __restrict__ fv, const float* __restrict__ mb,
             const int* __restrict__ ncand, const int* __restrict__ cand_pix,
             float* __restrict__ cand_val) {
    int nct = ncand[0]; if (nct > 64) nct = 64;
    int c0 = blockIdx.y * 4;
    if (c0 >= nct) return;
    int t = threadIdx.x, wid = t >> 6, lane = t & 63;

    int p0i = cand_pix[c0];
    int p1i = cand_pix[c0 + 1 < nct ? c0 + 1 : c0];
    int p2i = cand_pix[c0 + 2 < nct ? c0 + 2 : c0];
    int p3i = cand_pix[c0 + 3 < nct ? c0 + 3 : c0];
    const float4* s0 = (const float4*)(fv + (size_t)p0i * 512) + lane * 2;
    const float4* s1 = (const float4*)(fv + (size_t)p1i * 512) + lane * 2;
    const float4* s2 = (const float4*)(fv + (size_t)p2i * 512) + lane * 2;
    const float4* s3 = (const float4*)(fv + (size_t)p3i * 512) + lane * 2;
    float4 ca0 = s0[0], ca1 = s0[1];
    float4 cb0 = s1[0], cb1 = s1[1];
    float4 cc0 = s2[0], cc1 = s2[1];
    float4 cd0 = s3[0], cd1 = s3[1];

    float m0v = INF_F, m1v = INF_F, m2v = INF_F, m3v = INF_F;
    int rbase = blockIdx.x * 64 + wid * 16;
    for (int i = 0; i < 16; ++i) {
        int r = rbase + i;
        if (r >= 25000) break;
        const float4* mp = (const float4*)(mb + (size_t)r * 512) + lane * 2;
        float4 x0 = mp[0], x1 = mp[1];
        float d, p0 = 0.f, p1 = 0.f, p2 = 0.f, p3 = 0.f;
        d = x0.x-ca0.x; p0 += d*d;  d = x0.y-ca0.y; p0 += d*d;  d = x0.z-ca0.z; p0 += d*d;  d = x0.w-ca0.w; p0 += d*d;
        d = x1.x-ca1.x; p0 += d*d;  d = x1.y-ca1.y; p0 += d*d;  d = x1.z-ca1.z; p0 += d*d;  d = x1.w-ca1.w; p0 += d*d;
        d = x0.x-cb0.x; p1 += d*d;  d = x0.y-cb0.y; p1 += d*d;  d = x0.z-cb0.z; p1 += d*d;  d = x0.w-cb0.w; p1 += d*d;
        d = x1.x-cb1.x; p1 += d*d;  d = x1.y-cb1.y; p1 += d*d;  d = x1.z-cb1.z; p1 += d*d;  d = x1.w-cb1.w; p1 += d*d;
        d = x0.x-cc0.x; p2 += d*d;  d = x0.y-cc0.y; p2 += d*d;  d = x0.z-cc0.z; p2 += d*d;  d = x0.w-cc0.w; p2 += d*d;
        d = x1.x-cc1.x; p2 += d*d;  d = x1.y-cc1.y; p2 += d*d;  d = x1.z-cc1.z; p2 += d*d;  d = x1.w-cc1.w; p2 += d*d;
        d = x0.x-cd0.x; p3 += d*d;  d = x0.y-cd0.y; p3 += d*d;  d = x0.z-cd0.z; p3 += d*d;  d = x0.w-cd0.w; p3 += d*d;
        d = x1.x-cd1.x; p3 += d*d;  d = x1.y-cd1.y; p3 += d*d;  d = x1.z-cd1.z; p3 += d*d;  d = x1.w-cd1.w; p3 += d*d;
        #pragma unroll
        for (int s = 1; s < 64; s <<= 1) {
            p0 += __shfl_xor(p0, s, 64);
            p1 += __shfl_xor(p1, s, 64);
            p2 += __shfl_xor(p2, s, 64);
            p3 += __shfl_xor(p3, s, 64);
        }
        m0v = fminf(m0v, p0); m1v = fminf(m1v, p1);
        m2v = fminf(m2v, p2); m3v = fminf(m3v, p3);
    }
    if (lane < 4 && c0 + lane < nct) {
        float mv = (lane == 0) ? m0v : (lane == 1) ? m1v : (lane == 2) ? m2v : m3v;
        atomicMin((unsigned*)&cand_val[c0 + lane], __float_as_uint(mv));
    }
}

// ---------------- exact argmax -> winning pixel (ties -> lower pixel index) ----------------
__global__ void k_argmax(const int* ncand, const int* cand_pix, const int* cand_batch,
                         const float* cand_val, int* sel_pix) {
    int b = blockIdx.x, lane = threadIdx.x;
    int n = ncand[0]; if (n > 64) n = 64;
    float v = -INF_F; int pix = 0x7fffffff;
    if (lane < n && cand_batch[lane] == b) { v = cand_val[lane]; pix = cand_pix[lane]; }
    #pragma unroll
    for (int s = 1; s < 64; s <<= 1) {
        float ov = __shfl_xor(v, s, 64); int oi = __shfl_xor(pix, s, 64);
        if (ov > v || (ov == v && oi < pix)) { v = ov; pix = oi; }
    }
    if (lane == 0) sel_pix[b] = (pix == 0x7fffffff) ? b * 1024 : pix;
}

// ---------------- exact fp32 distances of winners, 4/block in NAMED registers ----------------
__global__ __launch_bounds__(256, 4)
void k_dists4(const float* __restrict__ fv, const float* __restrict__ mb,
              const int* __restrict__ sel_pix, float* __restrict__ exact_d) {
    int bg = blockIdx.y * 4;                 // batch group: 0..3 or 4..7
    int t = threadIdx.x, wid = t >> 6, lane = t & 63;

    const float4* s0 = (const float4*)(fv + (size_t)sel_pix[bg + 0] * 512) + lane * 2;
    const float4* s1 = (const float4*)(fv + (size_t)sel_pix[bg + 1] * 512) + lane * 2;
    const float4* s2 = (const float4*)(fv + (size_t)sel_pix[bg + 2] * 512) + lane * 2;
    const float4* s3 = (const float4*)(fv + (size_t)sel_pix[bg + 3] * 512) + lane * 2;
    float4 ca0 = s0[0], ca1 = s0[1];
    float4 cb0 = s1[0], cb1 = s1[1];
    float4 cc0 = s2[0], cc1 = s2[1];
    float4 cd0 = s3[0], cd1 = s3[1];

    int rbase = blockIdx.x * 64 + wid * 16;
    for (int i = 0; i < 16; ++i) {
        int r = rbase + i;
        if (r >= 25000) break;
        const float4* mp = (const float4*)(mb + (size_t)r * 512) + lane * 2;
        float4 x0 = mp[0], x1 = mp[1];
        float d, p0 = 0.f, p1 = 0.f, p2 = 0.f, p3 = 0.f;
        d = x0.x-ca0.x; p0 += d*d;  d = x0.y-ca0.y; p0 += d*d;  d = x0.z-ca0.z; p0 += d*d;  d = x0.w-ca0.w; p0 += d*d;
        d = x1.x-ca1.x; p0 += d*d;  d = x1.y-ca1.y; p0 += d*d;  d = x1.z-ca1.z; p0 += d*d;  d = x1.w-ca1.w; p0 += d*d;
        d = x0.x-cb0.x; p1 += d*d;  d = x0.y-cb0.y; p1 += d*d;  d = x0.z-cb0.z; p1 += d*d;  d = x0.w-cb0.w; p1 += d*d;
        d = x1.x-cb1.x; p1 += d*d;  d = x1.y-cb1.y; p1 += d*d;  d = x1.z-cb1.z; p1 += d*d;  d = x1.w-cb1.w; p1 += d*d;
        d = x0.x-cc0.x; p2 += d*d;  d = x0.y-cc0.y; p2 += d*d;  d = x0.z-cc0.z; p2 += d*d;  d = x0.w-cc0.w; p2 += d*d;
        d = x1.x-cc1.x; p2 += d*d;  d = x1.y-cc1.y; p2 += d*d;  d = x1.z-cc1.z; p2 += d*d;  d = x1.w-cc1.w; p2 += d*d;
        d = x0.x-cd0.x; p3 += d*d;  d = x0.y-cd0.y; p3 += d*d;  d = x0.z-cd0.z; p3 += d*d;  d = x0.w-cd0.w; p3 += d*d;
        d = x1.x-cd1.x; p3 += d*d;  d = x1.y-cd1.y; p3 += d*d;  d = x1.z-cd1.z; p3 += d*d;  d = x1.w-cd1.w; p3 += d*d;
        #pragma unroll
        for (int s = 1; s < 64; s <<= 1) {
            p0 += __shfl_xor(p0, s, 64);
            p1 += __shfl_xor(p1, s, 64);
            p2 += __shfl_xor(p2, s, 64);
            p3 += __shfl_xor(p3, s, 64);
        }
        if (lane < 4) {
            float pv = (lane == 0) ? p0 : (lane == 1) ? p1 : (lane == 2) ? p2 : p3;
            exact_d[(size_t)(bg + lane) * 25000 + r] = pv;
        }
    }
}

// ---------------- top-b (ascending dist, jax tie order) + softmax, 1024 threads ----------------
__global__ __launch_bounds__(1024)
void k_final(const float* __restrict__ exact_d, const int* __restrict__ bptr,
             float* __restrict__ out_img) {
    __shared__ float rv[16]; __shared__ int ri[16];
    __shared__ float seld[128];
    __shared__ float lastV_s; __shared__ int lastI_s;
    int b = blockIdx.x, t = threadIdx.x, wid = t >> 6, lane = t & 63;
    int bval = bptr[0]; if (bval > 128) bval = 128; if (bval < 1) bval = 1;
    const float* dv = exact_d + (size_t)b * 25000;
    float lastV = -INF_F; int lastI = -1;
    for (int k = 0; k < bval; ++k) {
        float bv = INF_F; int bi = 0x7fffffff;
        for (int r = t; r < 25000; r += 1024) {
            float vv = dv[r];
            bool after = (vv > lastV) || (vv == lastV && r > lastI);
            if (after && (vv < bv || (vv == bv && r < bi))) { bv = vv; bi = r; }
        }
        #pragma unroll
        for (int s = 1; s < 64; s <<= 1) {
            float ov = __shfl_xor(bv, s, 64); int oi = __shfl_xor(bi, s, 64);
            if (ov < bv || (ov == bv && oi < bi)) { bv = ov; bi = oi; }
        }
        if (lane == 0) { rv[wid] = bv; ri[wid] = bi; }
        __syncthreads();
        if (t == 0) {
            float fbv = rv[0]; int fbi = ri[0];
            for (int w = 1; w < 16; ++w)
                if (rv[w] < fbv || (rv[w] == fbv && ri[w] < fbi)) { fbv = rv[w]; fbi = ri[w]; }
            seld[k] = sqrtf(fbv);
            lastV_s = fbv; lastI_s = fbi;
        }
        __syncthreads();
        lastV = lastV_s; lastI = lastI_s;
    }
    if (t == 0) {
        float d0 = seld[0];
        float img = d0;
        if (bval > 1) {
            float m = -INF_F;
            for (int k = 0; k < bval; ++k) m = fmaxf(m, seld[k]);
            float s = 0.f;
            for (int k = 0; k < bval; ++k) s += expf(seld[k] - m);
            float p0 = expf(seld[0] - m) / s;
            img = d0 * (1.0f - p0);
        }
        out_img[b] = img;
    }
}

extern "C" void kernel_launch(void* const* d_in, const int* in_sizes, int n_in,
                              void* d_out, int out_size, void* d_ws, size_t ws_size,
                              hipStream_t stream) {
    const float* fv = (const float*)d_in[0];   // 8192 x 512
    const float* mb = (const float*)d_in[1];   // 25000 x 512
    const int*   bp = (const int*)d_in[2];     // scalar b
    float* out = (float*)d_out;                // [0..8191]=pixel_scores, [8192..8199]=image_scores

    char* w = (char*)d_ws;                     // ~35 MB total (same footprint as R5, which passed)
    unsigned short* fvb = (unsigned short*)w;                       // 8,388,608 B
    unsigned short* mbb = (unsigned short*)(w + 8388608);           // 25,600,000 B
    size_t o = 8388608 + 25600000;
    float* fnorm    = (float*)(w + o); o += 32768;
    float* mnorm    = (float*)(w + o); o += 100352;
    float* ps_sq    = (float*)(w + o); o += 32768;
    int*   ncand    = (int*)(w + o);   o += 256;
    int*   cand_pix = (int*)(w + o);   o += 256;
    int*   cand_bat = (int*)(w + o);   o += 256;
    float* cand_val = (float*)(w + o); o += 256;
    int*   sel_pix  = (int*)(w + o);   o += 256;
    float* exact_d  = (float*)(w + o); o += 800000;    // 8 x 25000 fp32

    k_conv<<<8298, 256, 0, stream>>>(fv, mb, fvb, mbb, fnorm, mnorm, ps_sq, ncand, cand_val);
    k_gemm_min<<<3136, 512, 0, stream>>>(fvb, mbb, fnorm, mnorm, ps_sq);
    k_cand<<<8, 256, 0, stream>>>(ps_sq, out, ncand, cand_pix, cand_bat);
    k_score<<<dim3(391, 16), 256, 0, stream>>>(fv, mb, ncand, cand_pix, cand_val);
    k_argmax<<<8, 64, 0, stream>>>(ncand, cand_pix, cand_bat, cand_val, sel_pix);
    k_dists4<<<dim3(391, 2), 256, 0, stream>>>(fv, mb, sel_pix, exact_d);
    k_final<<<8, 1024, 0, stream>>>(exact_d, bp, out + 8192);
}

// Round 7
// 480.522 us; speedup vs baseline: 1.1360x; 1.1360x over previous
//
#include <hip/hip_runtime.h>
#include <hip/hip_bf16.h>

typedef __attribute__((ext_vector_type(8))) short short8;
typedef __attribute__((ext_vector_type(4))) float f32x4;

#define INF_F 3.4e38f

__device__ __forceinline__ void gload16(const void* g, void* l) {
    __builtin_amdgcn_global_load_lds((const __attribute__((address_space(1))) unsigned*)g,
                                     (__attribute__((address_space(3))) unsigned*)l, 16, 0, 0);
}

// ---------------- fp32 -> bf16 + row norms (512 cols) for BOTH fv and mb, + init ----------------
__global__ void k_conv(const float* __restrict__ fv, const float* __restrict__ mbp,
                       unsigned short* __restrict__ fvb, unsigned short* __restrict__ mbb,
                       float* __restrict__ fnorm, float* __restrict__ mnorm,
                       float* ps_sq, int* ncand, float* cand_val) {
    int t = threadIdx.x, wid = t >> 6, lane = t & 63;
    if (blockIdx.x == 0) {
        if (t == 0) ncand[0] = 0;
        if (t < 64) ((unsigned*)cand_val)[t] = 0x7f800000u;
    }
    int row = blockIdx.x * 4 + wid;
    const float* in; unsigned short* outb; float* norm; int r;
    if (row < 8192) {
        in = fv; outb = fvb; norm = fnorm; r = row;
        if (lane == 0) ((unsigned*)ps_sq)[row] = 0x7f800000u;   // +inf init
    } else if (row < 33192) {
        in = mbp; outb = mbb; norm = mnorm; r = row - 8192;
    } else return;
    const float4* p = (const float4*)(in + (size_t)r * 512) + lane * 2;
    float4 a = p[0], b = p[1];
    float n = a.x*a.x + a.y*a.y + a.z*a.z + a.w*a.w
            + b.x*b.x + b.y*b.y + b.z*b.z + b.w*b.w;
    float vals[8] = {a.x, a.y, a.z, a.w, b.x, b.y, b.z, b.w};
    unsigned short h[8];
    #pragma unroll
    for (int e = 0; e < 8; ++e) {
        unsigned u = __float_as_uint(vals[e]);
        h[e] = (unsigned short)((u + 0x7fffu + ((u >> 16) & 1u)) >> 16);  // RNE
    }
    *(uint4*)(outb + (size_t)r * 512 + lane * 8) = *(uint4*)h;
    #pragma unroll
    for (int s = 1; s < 64; s <<= 1) n += __shfl_xor(n, s, 64);
    if (lane == 0) norm[r] = n;
}

// ---------------- fused GEMM + per-row min (R5-proven m97 structure; K=512 regime) ----------------
__global__ __launch_bounds__(256, 2)
void k_gemm_min(const unsigned short* __restrict__ A, const unsigned short* __restrict__ B,
                const float* __restrict__ fnorm, const float* __restrict__ mnorm,
                float* __restrict__ ps_sq) {
    __shared__ unsigned short At[128 * 64];
    __shared__ unsigned short Bt[128 * 64];
    int tid = threadIdx.x, wid = tid >> 6, lane = tid & 63;
    int bid = blockIdx.x;
    int pos = bid >> 3;
    int rb = ((bid & 7) << 3) | (pos & 7);   // 0..63
    int cb = pos >> 3;                        // 0..195
    int brow = rb * 128, bcol = cb * 128;
    int wm = (wid >> 1) * 64, wn = (wid & 1) * 64;

    f32x4 acc[4][4] = {};
    int lr = lane >> 3;
    int lkswz = ((lane & 7) ^ lr) * 8;        // pre-swizzled source column (elems)

    for (int k0 = 0; k0 < 512; k0 += 64) {
        #pragma unroll
        for (int c = 0; c < 4; ++c) {
            int ch = wid + c * 4;
            int row = ch * 8 + lr;
            gload16(A + (size_t)(brow + row) * 512 + k0 + lkswz, &At[ch * 512]);
            int srow = bcol + row; if (srow > 24999) srow = 24999;
            gload16(B + (size_t)srow * 512 + k0 + lkswz, &Bt[ch * 512]);
        }
        __syncthreads();
        #pragma unroll
        for (int kk = 0; kk < 2; ++kk) {
            short8 af[4], bf[4];
            int ko = kk * 32 + (lane >> 4) * 8;
            #pragma unroll
            for (int mi = 0; mi < 4; ++mi) {
                int r = wm + mi * 16 + (lane & 15);
                af[mi] = *(const short8*)&At[r * 64 + (ko ^ ((r & 7) << 3))];
            }
            #pragma unroll
            for (int ni = 0; ni < 4; ++ni) {
                int r = wn + ni * 16 + (lane & 15);
                bf[ni] = *(const short8*)&Bt[r * 64 + (ko ^ ((r & 7) << 3))];
            }
            #pragma unroll
            for (int mi = 0; mi < 4; ++mi)
                #pragma unroll
                for (int ni = 0; ni < 4; ++ni)
                    acc[mi][ni] = __builtin_amdgcn_mfma_f32_16x16x32_bf16(af[mi], bf[ni], acc[mi][ni], 0, 0, 0);
        }
        __syncthreads();
    }

    float mnv[4];
    #pragma unroll
    for (int ni = 0; ni < 4; ++ni) {
        int col = bcol + wn + ni * 16 + (lane & 15);
        mnv[ni] = (col < 25000) ? mnorm[col] : INF_F;
    }
    #pragma unroll
    for (int mi = 0; mi < 4; ++mi) {
        #pragma unroll
        for (int r = 0; r < 4; ++r) {
            float v = INF_F;
            #pragma unroll
            for (int ni = 0; ni < 4; ++ni) v = fminf(v, mnv[ni] - 2.0f * acc[mi][ni][r]);
            #pragma unroll
            for (int s = 1; s < 16; s <<= 1) v = fminf(v, __shfl_xor(v, s, 64));
            if ((lane & 15) == 0) {
                int row = brow + wm + mi * 16 + (lane >> 4) * 4 + r;
                float sq = v + fnorm[row];
                atomicMin((unsigned*)&ps_sq[row], __float_as_uint(sq));
            }
        }
    }
}

// ---------------- out0 + per-batch candidate gather ----------------
__global__ void k_cand(const float* __restrict__ ps_sq, float* __restrict__ out0,
                       int* ncand, int* cand_pix, int* cand_batch) {
    __shared__ float smax[4];
    __shared__ int scnt;
    int b = blockIdx.x, t = threadIdx.x, wid = t >> 6, lane = t & 63;
    const float* base = ps_sq + b * 1024;
    float v[4]; float m = -INF_F;
    #pragma unroll
    for (int i = 0; i < 4; ++i) {
        v[i] = base[t + i * 256];
        out0[b * 1024 + t + i * 256] = sqrtf(fmaxf(v[i], 0.0f));
        m = fmaxf(m, v[i]);
    }
    #pragma unroll
    for (int s = 1; s < 64; s <<= 1) m = fmaxf(m, __shfl_xor(m, s, 64));
    if (lane == 0) smax[wid] = m;
    if (t == 0) scnt = 0;
    __syncthreads();
    float bm = fmaxf(fmaxf(smax[0], smax[1]), fmaxf(smax[2], smax[3]));
    #pragma unroll
    for (int i = 0; i < 4; ++i) {
        if (v[i] >= bm - 8.0f) {            // margin >> 2x worst-case bf16 dot error
            int s = atomicAdd(&scnt, 1);
            if (s < 8) {
                int g = atomicAdd(ncand, 1);
                if (g < 64) { cand_pix[g] = b * 1024 + t + i * 256; cand_batch[g] = b; }
            }
        }
    }
}

// ---------------- exact fp32 min-dist, 4 candidates/block in NAMED registers ----------------
__global__ __launch_bounds__(256, 4)
void k_score(const float* __restrict__ fv, const float* __restrict__ mb,
             const int* __restrict__ ncand, const int* __restrict__ cand_pix,
             float* __restrict__ cand_val) {
    int nct = ncand[0]; if (nct > 64) nct = 64;
    int c0 = blockIdx.y * 4;
    if (c0 >= nct) return;
    int t = threadIdx.x, wid = t >> 6, lane = t & 63;

    int p0i = cand_pix[c0];
    int p1i = cand_pix[c0 + 1 < nct ? c0 + 1 : c0];
    int p2i = cand_pix[c0 + 2 < nct ? c0 + 2 : c0];
    int p3i = cand_pix[c0 + 3 < nct ? c0 + 3 : c0];
    const float4* s0 = (const float4*)(fv + (size_t)p0i * 512) + lane * 2;
    const float4* s1 = (const float4*)(fv + (size_t)p1i * 512) + lane * 2;
    const float4* s2 = (const float4*)(fv + (size_t)p2i * 512) + lane * 2;
    const float4* s3 = (const float4*)(fv + (size_t)p3i * 512) + lane * 2;
    float4 ca0 = s0[0], ca1 = s0[1];
    float4 cb0 = s1[0], cb1 = s1[1];
    float4 cc0 = s2[0], cc1 = s2[1];
    float4 cd0 = s3[0], cd1 = s3[1];

    float m0v = INF_F, m1v = INF_F, m2v = INF_F, m3v = INF_F;
    int rbase = blockIdx.x * 64 + wid * 16;
    for (int i = 0; i < 16; ++i) {
        int r = rbase + i;
        if (r >= 25000) break;
        const float4* mp = (const float4*)(mb + (size_t)r * 512) + lane * 2;
        float4 x0 = mp[0], x1 = mp[1];
        float d, p0 = 0.f, p1 = 0.f, p2 = 0.f, p3 = 0.f;
        d = x0.x-ca0.x; p0 += d*d;  d = x0.y-ca0.y; p0 += d*d;  d = x0.z-ca0.z; p0 += d*d;  d = x0.w-ca0.w; p0 += d*d;
        d = x1.x-ca1.x; p0 += d*d;  d = x1.y-ca1.y; p0 += d*d;  d = x1.z-ca1.z; p0 += d*d;  d = x1.w-ca1.w; p0 += d*d;
        d = x0.x-cb0.x; p1 += d*d;  d = x0.y-cb0.y; p1 += d*d;  d = x0.z-cb0.z; p1 += d*d;  d = x0.w-cb0.w; p1 += d*d;
        d = x1.x-cb1.x; p1 += d*d;  d = x1.y-cb1.y; p1 += d*d;  d = x1.z-cb1.z; p1 += d*d;  d = x1.w-cb1.w; p1 += d*d;
        d = x0.x-cc0.x; p2 += d*d;  d = x0.y-cc0.y; p2 += d*d;  d = x0.z-cc0.z; p2 += d*d;  d = x0.w-cc0.w; p2 += d*d;
        d = x1.x-cc1.x; p2 += d*d;  d = x1.y-cc1.y; p2 += d*d;  d = x1.z-cc1.z; p2 += d*d;  d = x1.w-cc1.w; p2 += d*d;
        d = x0.x-cd0.x; p3 += d*d;  d = x0.y-cd0.y; p3 += d*d;  d = x0.z-cd0.z; p3 += d*d;  d = x0.w-cd0.w; p3 += d*d;
        d = x1.x-cd1.x; p3 += d*d;  d = x1.y-cd1.y; p3 += d*d;  d = x1.z-cd1.z; p3 += d*d;  d = x1.w-cd1.w; p3 += d*d;
        #pragma unroll
        for (int s = 1; s < 64; s <<= 1) {
            p0 += __shfl_xor(p0, s, 64);
            p1 += __shfl_xor(p1, s, 64);
            p2 += __shfl_xor(p2, s, 64);
            p3 += __shfl_xor(p3, s, 64);
        }
        m0v = fminf(m0v, p0); m1v = fminf(m1v, p1);
        m2v = fminf(m2v, p2); m3v = fminf(m3v, p3);
    }
    if (lane < 4 && c0 + lane < nct) {
        float mv = (lane == 0) ? m0v : (lane == 1) ? m1v : (lane == 2) ? m2v : m3v;
        atomicMin((unsigned*)&cand_val[c0 + lane], __float_as_uint(mv));
    }
}

// ---------------- winners' exact distances; argmax folded in (redundant per block) ----------------
__global__ __launch_bounds__(256, 4)
void k_dists4(const float* __restrict__ fv, const float* __restrict__ mb,
              const int* __restrict__ ncand, const int* __restrict__ cand_pix,
              const int* __restrict__ cand_batch, const float* __restrict__ cand_val,
              float* __restrict__ exact_d) {
    int bg = blockIdx.y * 4;                 // batch group: 0..3 or 4..7
    int t = threadIdx.x, wid = t >> 6, lane = t & 63;
    int n = ncand[0]; if (n > 64) n = 64;

    // per-batch exact argmax over candidate slots (ties -> lower pixel index)
    int sp[4];
    #pragma unroll
    for (int q = 0; q < 4; ++q) {
        float v = -INF_F; int pix = 0x7fffffff;
        if (lane < n && cand_batch[lane] == bg + q) { v = cand_val[lane]; pix = cand_pix[lane]; }
        #pragma unroll
        for (int s = 1; s < 64; s <<= 1) {
            float ov = __shfl_xor(v, s, 64); int oi = __shfl_xor(pix, s, 64);
            if (ov > v || (ov == v && oi < pix)) { v = ov; pix = oi; }
        }
        sp[q] = (pix == 0x7fffffff) ? (bg + q) * 1024 : pix;
    }

    const float4* s0 = (const float4*)(fv + (size_t)sp[0] * 512) + lane * 2;
    const float4* s1 = (const float4*)(fv + (size_t)sp[1] * 512) + lane * 2;
    const float4* s2 = (const float4*)(fv + (size_t)sp[2] * 512) + lane * 2;
    const float4* s3 = (const float4*)(fv + (size_t)sp[3] * 512) + lane * 2;
    float4 ca0 = s0[0], ca1 = s0[1];
    float4 cb0 = s1[0], cb1 = s1[1];
    float4 cc0 = s2[0], cc1 = s2[1];
    float4 cd0 = s3[0], cd1 = s3[1];

    int rbase = blockIdx.x * 64 + wid * 16;
    for (int i = 0; i < 16; ++i) {
        int r = rbase + i;
        if (r >= 25000) break;
        const float4* mp = (const float4*)(mb + (size_t)r * 512) + lane * 2;
        float4 x0 = mp[0], x1 = mp[1];
        float d, p0 = 0.f, p1 = 0.f, p2 = 0.f, p3 = 0.f;
        d = x0.x-ca0.x; p0 += d*d;  d = x0.y-ca0.y; p0 += d*d;  d = x0.z-ca0.z; p0 += d*d;  d = x0.w-ca0.w; p0 += d*d;
        d = x1.x-ca1.x; p0 += d*d;  d = x1.y-ca1.y; p0 += d*d;  d = x1.z-ca1.z; p0 += d*d;  d = x1.w-ca1.w; p0 += d*d;
        d = x0.x-cb0.x; p1 += d*d;  d = x0.y-cb0.y; p1 += d*d;  d = x0.z-cb0.z; p1 += d*d;  d = x0.w-cb0.w; p1 += d*d;
        d = x1.x-cb1.x; p1 += d*d;  d = x1.y-cb1.y; p1 += d*d;  d = x1.z-cb1.z; p1 += d*d;  d = x1.w-cb1.w; p1 += d*d;
        d = x0.x-cc0.x; p2 += d*d;  d = x0.y-cc0.y; p2 += d*d;  d = x0.z-cc0.z; p2 += d*d;  d = x0.w-cc0.w; p2 += d*d;
        d = x1.x-cc1.x; p2 += d*d;  d = x1.y-cc1.y; p2 += d*d;  d = x1.z-cc1.z; p2 += d*d;  d = x1.w-cc1.w; p2 += d*d;
        d = x0.x-cd0.x; p3 += d*d;  d = x0.y-cd0.y; p3 += d*d;  d = x0.z-cd0.z; p3 += d*d;  d = x0.w-cd0.w; p3 += d*d;
        d = x1.x-cd1.x; p3 += d*d;  d = x1.y-cd1.y; p3 += d*d;  d = x1.z-cd1.z; p3 += d*d;  d = x1.w-cd1.w; p3 += d*d;
        #pragma unroll
        for (int s = 1; s < 64; s <<= 1) {
            p0 += __shfl_xor(p0, s, 64);
            p1 += __shfl_xor(p1, s, 64);
            p2 += __shfl_xor(p2, s, 64);
            p3 += __shfl_xor(p3, s, 64);
        }
        if (lane < 4) {
            float pv = (lane == 0) ? p0 : (lane == 1) ? p1 : (lane == 2) ? p2 : p3;
            exact_d[(size_t)(bg + lane) * 25000 + r] = pv;
        }
    }
}

// ---------------- single-pass top-b (ascending dist, jax tie order) + softmax ----------------
__global__ __launch_bounds__(1024)
void k_final(const float* __restrict__ exact_d, const int* __restrict__ bptr,
             float* __restrict__ out_img) {
    __shared__ float wbv[16]; __shared__ int wbi[16];
    __shared__ float seld[128];
    __shared__ float gbv_s; __shared__ int gbi_s;
    int b = blockIdx.x, t = threadIdx.x, wid = t >> 6, lane = t & 63;
    int bval = bptr[0]; if (bval > 128) bval = 128; if (bval < 1) bval = 1;
    const float* dv = exact_d + (size_t)b * 25000;

    if (bval <= 16) {
        // per-thread sorted top-16 (static indices only -> stays in registers)
        float tv[16]; int ti[16];
        #pragma unroll
        for (int k = 0; k < 16; ++k) { tv[k] = INF_F; ti[k] = 0x7fffffff; }
        for (int r = t; r < 25000; r += 1024) {
            float cv = dv[r]; int ci = r;
            #pragma unroll
            for (int k = 0; k < 16; ++k) {
                bool better = (cv < tv[k]) || (cv == tv[k] && ci < ti[k]);
                if (better) {
                    float t1 = tv[k]; tv[k] = cv; cv = t1;
                    int   t2 = ti[k]; ti[k] = ci; ci = t2;
                }
            }
        }
        // bval extraction rounds; winning thread shifts its list (static unroll)
        for (int k = 0; k < bval; ++k) {
            float bv = tv[0]; int bi = ti[0];
            #pragma unroll
            for (int s = 1; s < 64; s <<= 1) {
                float ov = __shfl_xor(bv, s, 64); int oi = __shfl_xor(bi, s, 64);
                if (ov < bv || (ov == bv && oi < bi)) { bv = ov; bi = oi; }
            }
            if (lane == 0) { wbv[wid] = bv; wbi[wid] = bi; }
            __syncthreads();
            if (t == 0) {
                float fb = wbv[0]; int fi = wbi[0];
                for (int w2 = 1; w2 < 16; ++w2)
                    if (wbv[w2] < fb || (wbv[w2] == fb && wbi[w2] < fi)) { fb = wbv[w2]; fi = wbi[w2]; }
                seld[k] = sqrtf(fb);
                gbv_s = fb; gbi_s = fi;
            }
            __syncthreads();
            if (tv[0] == gbv_s && ti[0] == gbi_s) {       // unique index -> exactly one thread
                #pragma unroll
                for (int k2 = 0; k2 < 15; ++k2) { tv[k2] = tv[k2 + 1]; ti[k2] = ti[k2 + 1]; }
                tv[15] = INF_F; ti[15] = 0x7fffffff;
            }
        }
    } else {
        // fallback: iterative passes (jax tie order)
        float lastV = -INF_F; int lastI = -1;
        for (int k = 0; k < bval; ++k) {
            float bv = INF_F; int bi = 0x7fffffff;
            for (int r = t; r < 25000; r += 1024) {
                float vv = dv[r];
                bool after = (vv > lastV) || (vv == lastV && r > lastI);
                if (after && (vv < bv || (vv == bv && r < bi))) { bv = vv; bi = r; }
            }
            #pragma unroll
            for (int s = 1; s < 64; s <<= 1) {
                float ov = __shfl_xor(bv, s, 64); int oi = __shfl_xor(bi, s, 64);
                if (ov < bv || (ov == bv && oi < bi)) { bv = ov; bi = oi; }
            }
            if (lane == 0) { wbv[wid] = bv; wbi[wid] = bi; }
            __syncthreads();
            if (t == 0) {
                float fb = wbv[0]; int fi = wbi[0];
                for (int w2 = 1; w2 < 16; ++w2)
                    if (wbv[w2] < fb || (wbv[w2] == fb && wbi[w2] < fi)) { fb = wbv[w2]; fi = wbi[w2]; }
                seld[k] = sqrtf(fb);
                gbv_s = fb; gbi_s = fi;
            }
            __syncthreads();
            lastV = gbv_s; lastI = gbi_s;
        }
    }

    if (t == 0) {
        float d0 = seld[0];
        float img = d0;
        if (bval > 1) {
            float m = -INF_F;
            for (int k = 0; k < bval; ++k) m = fmaxf(m, seld[k]);
            float s = 0.f;
            for (int k = 0; k < bval; ++k) s += expf(seld[k] - m);
            float p0 = expf(seld[0] - m) / s;
            img = d0 * (1.0f - p0);
        }
        out_img[b] = img;
    }
}

extern "C" void kernel_launch(void* const* d_in, const int* in_sizes, int n_in,
                              void* d_out, int out_size, void* d_ws, size_t ws_size,
                              hipStream_t stream) {
    const float* fv = (const float*)d_in[0];   // 8192 x 512
    const float* mb = (const float*)d_in[1];   // 25000 x 512
    const int*   bp = (const int*)d_in[2];     // scalar b
    float* out = (float*)d_out;                // [0..8191]=pixel_scores, [8192..8199]=image_scores

    char* w = (char*)d_ws;                     // ~35 MB total (proven footprint)
    unsigned short* fvb = (unsigned short*)w;                       // 8,388,608 B
    unsigned short* mbb = (unsigned short*)(w + 8388608);           // 25,600,000 B
    size_t o = 8388608 + 25600000;
    float* fnorm    = (float*)(w + o); o += 32768;
    float* mnorm    = (float*)(w + o); o += 100352;
    float* ps_sq    = (float*)(w + o); o += 32768;
    int*   ncand    = (int*)(w + o);   o += 256;
    int*   cand_pix = (int*)(w + o);   o += 256;
    int*   cand_bat = (int*)(w + o);   o += 256;
    float* cand_val = (float*)(w + o); o += 256;
    int*   sel_unused = (int*)(w + o); o += 256;
    float* exact_d  = (float*)(w + o); o += 800000;    // 8 x 25000 fp32
    (void)sel_unused;

    k_conv<<<8298, 256, 0, stream>>>(fv, mb, fvb, mbb, fnorm, mnorm, ps_sq, ncand, cand_val);
    k_gemm_min<<<12544, 256, 0, stream>>>(fvb, mbb, fnorm, mnorm, ps_sq);
    k_cand<<<8, 256, 0, stream>>>(ps_sq, out, ncand, cand_pix, cand_bat);
    k_score<<<dim3(391, 16), 256, 0, stream>>>(fv, mb, ncand, cand_pix, cand_val);
    k_dists4<<<dim3(391, 2), 256, 0, stream>>>(fv, mb, ncand, cand_pix, cand_bat, cand_val, exact_d);
    k_final<<<8, 1024, 0, stream>>>(exact_d, bp, out + 8192);
}